// Round 2
// baseline (675.244 us; speedup 1.0000x reference)
//
#include <hip/hip_runtime.h>

// BlockDiagonalAggregator: out[b,:] = sum_k softmax_k(<keys[sigma[b,k]], h[b,k,:]>) * h[b,k,:]
// B=4096, K=64, D=512, N_AGENTS=64 (sigma==64 -> unassigned -> logit=-1e9)
//
// One block (1024 threads = 16 waves) per batch row b; h[b] (128 KiB) is read
// from HBM exactly ONCE and cached in registers: wave w owns k-rows 4w..4w+3,
// lane l owns dims [4l,4l+4) and [256+4l,256+4l+4) of each row (32 f32/thread).
// __launch_bounds__(1024,8) caps VGPRs at 64 -> 32 waves/CU (full occupancy),
// which is what the latency-bound R1 version (>128 VGPR, 8 waves/CU) lacked.

constexpr int K  = 64;
constexpr int D  = 512;
constexpr int NA = 64;
#define NEG_INF (-1e9f)

__global__ __launch_bounds__(1024, 8)
void bda_kernel(const float* __restrict__ h, const float* __restrict__ keys,
                const int* __restrict__ sigma, float* __restrict__ out) {
    const int b    = blockIdx.x;
    const int tid  = threadIdx.x;
    const int w    = tid >> 6;    // wave 0..15
    const int lane = tid & 63;

    __shared__ float lg[K];                        // logits
    __shared__ __align__(16) float obuf[16 * D];   // per-wave partials (32 KiB)

    const float* hb = h + (size_t)b * (K * D);

    // Register cache: 4 rows x 8 dims = 32 VGPRs
    float4 hlo[4], hhi[4];

    // ---- Phase 1: load h (dense float4 per lane), compute logits ------------
#pragma unroll
    for (int kk = 0; kk < 4; ++kk) {
        const int k = (w << 2) + kk;
        const float* row = hb + k * D;
        hlo[kk] = ((const float4*)row)[lane];            // dims 4l..4l+3
        hhi[kk] = ((const float4*)(row + 256))[lane];    // dims 256+4l..

        const int sg = sigma[b * K + k];   // wave-uniform
        float dacc = NEG_INF;
        if (sg < NA) {                     // wave-uniform branch
            const float* krow = keys + sg * D;
            const float4 klo = ((const float4*)krow)[lane];
            const float4 khi = ((const float4*)(krow + 256))[lane];
            dacc = hlo[kk].x * klo.x + hlo[kk].y * klo.y
                 + hlo[kk].z * klo.z + hlo[kk].w * klo.w
                 + hhi[kk].x * khi.x + hhi[kk].y * khi.y
                 + hhi[kk].z * khi.z + hhi[kk].w * khi.w;
#pragma unroll
            for (int off = 32; off > 0; off >>= 1)
                dacc += __shfl_xor(dacc, off, 64);
        }
        if (lane == 0) lg[k] = dacc;
    }
    __syncthreads();

    // ---- Softmax stats: butterfly over the 64 logits (each wave redundant) --
    const float v = lg[lane];
    float m = v;
#pragma unroll
    for (int off = 32; off > 0; off >>= 1)
        m = fmaxf(m, __shfl_xor(m, off, 64));
    float s = __expf(v - m);
#pragma unroll
    for (int off = 32; off > 0; off >>= 1)
        s += __shfl_xor(s, off, 64);
    const float inv_s = 1.0f / s;
    // All-unassigned edge: every lg = -1e9 -> m = -1e9, s = 64, alpha = 1/64,
    // identical to the reference's softmax over all-(-1e9) logits.

    // ---- Phase 2: weighted pooling from the register cache ------------------
    float4 a0 = make_float4(0.f, 0.f, 0.f, 0.f);
    float4 a1 = make_float4(0.f, 0.f, 0.f, 0.f);
#pragma unroll
    for (int kk = 0; kk < 4; ++kk) {
        const int k = (w << 2) + kk;
        const float al = __expf(lg[k] - m) * inv_s;  // wave-uniform LDS broadcast
        a0.x += al * hlo[kk].x;  a0.y += al * hlo[kk].y;
        a0.z += al * hlo[kk].z;  a0.w += al * hlo[kk].w;
        a1.x += al * hhi[kk].x;  a1.y += al * hhi[kk].y;
        a1.z += al * hhi[kk].z;  a1.w += al * hhi[kk].w;
    }
    float* ob = obuf + w * D;
    ((float4*)ob)[lane]         = a0;   // dims 4l..4l+3
    ((float4*)(ob + 256))[lane] = a1;   // dims 256+4l..
    __syncthreads();

    // ---- Cross-wave reduce + coalesced store --------------------------------
    if (tid < D) {
        float r = 0.f;
#pragma unroll
        for (int w2 = 0; w2 < 16; ++w2)
            r += obuf[w2 * D + tid];      // stride-1 across lanes: conflict-free
        out[(size_t)b * D + tid] = r;
    }
}

extern "C" void kernel_launch(void* const* d_in, const int* in_sizes, int n_in,
                              void* d_out, int out_size, void* d_ws, size_t ws_size,
                              hipStream_t stream) {
    const float* h     = (const float*)d_in[0];
    const float* keys  = (const float*)d_in[1];
    const int*   sigma = (const int*)d_in[2];
    float*       out   = (float*)d_out;
    const int B = in_sizes[2] / K;   // sigma has B*K elements
    bda_kernel<<<dim3(B), dim3(1024), 0, stream>>>(h, keys, sigma, out);
}